// Round 1
// baseline (1383.529 us; speedup 1.0000x reference)
//
#include <hip/hip_runtime.h>
#include <stdint.h>

// ---------------- problem constants ----------------
#define N_E   8192
#define EDIM  256
#define NB    16
#define HH    32
#define WW    32
#define HW    1024            // H*W
#define NI    16384           // NB*HW (rows of zf)
#define NELEM 4194304         // NB*EDIM*HW

// output flat offsets (reference return order)
#define O_ZQ   0
#define O_LOSS 4194304
#define O_DIST 4194305
#define O_IDX  4194817
#define O_ZFL  4211201
#define O_CBV  8405505
#define O_TMD  8405506

// workspace byte offsets
#define WS_PMIN 0            // u64  * 16384
#define WS_IDX  131072       // i32  * 16384
#define WS_DMIN 196608       // f32  * 16384
#define WS_E2   262144       // f32  * 8192
#define WS_Z2   294912       // f32  * 16384
#define WS_MSE  360448       // double
#define WS_D1P  360512       // f32  * 8*8192*2

__device__ __forceinline__ int row8(int ty, int r) {
    return (r < 4) ? (ty * 4 + r) : (64 + ty * 4 + (r - 4));
}

// ---------------- init (ws is poisoned 0xAA every launch) ----------------
__global__ void k_init(unsigned long long* __restrict__ pmin, double* __restrict__ mse) {
    int t = blockIdx.x * 256 + threadIdx.x;
    if (t < NI) pmin[t] = 0xFFFFFFFFFFFFFFFFull;
    if (t == 0) *mse = 0.0;
}

// ---------------- e2[n] = sum_c emb[n,c]^2 ----------------
__global__ void k_e2(const float* __restrict__ emb, float* __restrict__ e2) {
    int row  = blockIdx.x * 4 + (threadIdx.x >> 6);
    int lane = threadIdx.x & 63;
    float4 v = *reinterpret_cast<const float4*>(emb + (size_t)row * EDIM + lane * 4);
    float s = v.x * v.x + v.y * v.y + v.z * v.z + v.w * v.w;
    #pragma unroll
    for (int m = 32; m; m >>= 1) s += __shfl_xor(s, m);
    if (lane == 0) e2[row] = s;
}

// ---------------- z2[i] = sum_c z[b,c,h,w]^2  (i = b*1024+hw) ----------------
__global__ void k_z2(const float* __restrict__ z, float* __restrict__ z2) {
    int i = blockIdx.x * 256 + threadIdx.x;
    int b = i >> 10, hw = i & 1023;
    const float* p = z + (size_t)b * EDIM * HW + hw;
    float s = 0.f;
    #pragma unroll 8
    for (int c = 0; c < EDIM; ++c) { float v = p[(size_t)c * HW]; s += v * v; }
    z2[i] = s;
}

// ---------------- fused GEMM + row-min/argmin over codebook ----------------
// d[i,n] = (z2_i + e2_n) - 2 * dot(zf_i, emb_n); per-i running (min, argmin)
// tile: 128 rows(i) x 128 cols(n) per step, 8 n-steps per block (n-split 1024)
__launch_bounds__(256)
__global__ void k_gemm_z(const float* __restrict__ z, const float* __restrict__ emb,
                         const float* __restrict__ z2, const float* __restrict__ e2,
                         unsigned long long* __restrict__ pmin) {
    __shared__ float a_lds[16][128];
    __shared__ float b_lds[16][128];
    const int t  = threadIdx.x;
    const int tx = t & 15, ty = t >> 4;
    const int i0 = blockIdx.x * 128;
    const int bb = i0 >> 10, hw0 = i0 & 1023;
    const int nbase = blockIdx.y * 1024;

    float minv[8], z2r[8];
    int   mini[8];
    #pragma unroll
    for (int r = 0; r < 8; ++r) {
        minv[r] = 3.4e38f; mini[r] = 0x7fffffff;
        z2r[r]  = z2[i0 + row8(ty, r)];
    }

    const int ak = t >> 4;           // A-stage: k row 0..15
    const int ax = (t & 15) * 4;     // A-stage: col offset
    const float* zbase = z + (size_t)bb * EDIM * HW + hw0;
    const int bj = t >> 1;           // B-stage: emb row within tile
    const int bc = (t & 1) * 8;      // B-stage: k offset 0/8

    for (int ns = 0; ns < 8; ++ns) {
        const int n0 = nbase + ns * 128;
        float acc[8][8];
        #pragma unroll
        for (int r = 0; r < 8; ++r)
            #pragma unroll
            for (int c = 0; c < 8; ++c) acc[r][c] = 0.f;

        for (int kc = 0; kc < 16; ++kc) {
            const int c0 = kc * 16;
            __syncthreads();
            // A: a_lds[k][x] = z[(bb*256 + c0+k)*1024 + hw0 + x]
            *reinterpret_cast<float4*>(&a_lds[ak][ax]) =
                *reinterpret_cast<const float4*>(zbase + (size_t)(c0 + ak) * HW + ax);
            *reinterpret_cast<float4*>(&a_lds[ak][ax + 64]) =
                *reinterpret_cast<const float4*>(zbase + (size_t)(c0 + ak) * HW + ax + 64);
            // B: b_lds[k][j] = emb[(n0+j)*256 + c0 + k]
            {
                const float4 u = *reinterpret_cast<const float4*>(emb + (size_t)(n0 + bj) * EDIM + c0 + bc);
                const float4 v = *reinterpret_cast<const float4*>(emb + (size_t)(n0 + bj) * EDIM + c0 + bc + 4);
                b_lds[bc + 0][bj] = u.x; b_lds[bc + 1][bj] = u.y;
                b_lds[bc + 2][bj] = u.z; b_lds[bc + 3][bj] = u.w;
                b_lds[bc + 4][bj] = v.x; b_lds[bc + 5][bj] = v.y;
                b_lds[bc + 6][bj] = v.z; b_lds[bc + 7][bj] = v.w;
            }
            __syncthreads();
            #pragma unroll
            for (int k = 0; k < 16; ++k) {
                const float4 a0 = *reinterpret_cast<const float4*>(&a_lds[k][ty * 4]);
                const float4 a1 = *reinterpret_cast<const float4*>(&a_lds[k][64 + ty * 4]);
                const float4 b0 = *reinterpret_cast<const float4*>(&b_lds[k][tx * 4]);
                const float4 b1 = *reinterpret_cast<const float4*>(&b_lds[k][64 + tx * 4]);
                const float av[8] = {a0.x, a0.y, a0.z, a0.w, a1.x, a1.y, a1.z, a1.w};
                const float bv[8] = {b0.x, b0.y, b0.z, b0.w, b1.x, b1.y, b1.z, b1.w};
                #pragma unroll
                for (int r = 0; r < 8; ++r)
                    #pragma unroll
                    for (int c = 0; c < 8; ++c)
                        acc[r][c] = fmaf(av[r], bv[c], acc[r][c]);
            }
        }
        // fold this 128-col block into running min
        const float4 e0 = *reinterpret_cast<const float4*>(&e2[n0 + tx * 4]);
        const float4 e1 = *reinterpret_cast<const float4*>(&e2[n0 + 64 + tx * 4]);
        const float ev[8] = {e0.x, e0.y, e0.z, e0.w, e1.x, e1.y, e1.z, e1.w};
        #pragma unroll
        for (int r = 0; r < 8; ++r) {
            #pragma unroll
            for (int c = 0; c < 8; ++c) {
                const float d = (z2r[r] + ev[c]) - 2.0f * acc[r][c];
                const int   n = n0 + ((c < 4) ? (tx * 4 + c) : (64 + tx * 4 + (c - 4)));
                if (d < minv[r]) { minv[r] = d; mini[r] = n; }   // strict <: first index wins
            }
        }
    }
    // reduce across tx lanes (lane = ty_local*16 + tx within the wave)
    #pragma unroll
    for (int r = 0; r < 8; ++r) {
        #pragma unroll
        for (int m = 1; m < 16; m <<= 1) {
            const float ov = __shfl_xor(minv[r], m);
            const int   oi = __shfl_xor(mini[r], m);
            if (ov < minv[r] || (ov == minv[r] && oi < mini[r])) { minv[r] = ov; mini[r] = oi; }
        }
        if (tx == 0) {
            const unsigned long long pk =
                ((unsigned long long)__float_as_uint(minv[r]) << 32) | (unsigned)mini[r];
            atomicMin(&pmin[i0 + row8(ty, r)], pk);
        }
    }
}

// ---------------- fused GEMM + per-column two-smallest (codebook d1) ----------------
// d1[m,n] = (e2_m + e2_n) - 2*dot(emb_m, emb_n); track 2 smallest over m per n
__launch_bounds__(256)
__global__ void k_gemm_d1(const float* __restrict__ emb, const float* __restrict__ e2,
                          float* __restrict__ d1p) {
    __shared__ float a_lds[16][128];
    __shared__ float b_lds[16][128];
    const int t  = threadIdx.x;
    const int tx = t & 15, ty = t >> 4;
    const int n0A   = blockIdx.x * 128;   // output columns (n) tile
    const int mbase = blockIdx.y * 1024;  // m split

    float v1[8], v2[8], e2a[8];
    #pragma unroll
    for (int r = 0; r < 8; ++r) { v1[r] = 3.4e38f; v2[r] = 3.4e38f; e2a[r] = e2[n0A + row8(ty, r)]; }

    const int aj = t >> 1;
    const int ac = (t & 1) * 8;

    for (int ms = 0; ms < 8; ++ms) {
        const int m0 = mbase + ms * 128;
        float acc[8][8];
        #pragma unroll
        for (int r = 0; r < 8; ++r)
            #pragma unroll
            for (int c = 0; c < 8; ++c) acc[r][c] = 0.f;

        for (int kc = 0; kc < 16; ++kc) {
            const int c0 = kc * 16;
            __syncthreads();
            {   // A: a_lds[k][x] = emb[(n0A+x)*256 + c0 + k]
                const float4 u = *reinterpret_cast<const float4*>(emb + (size_t)(n0A + aj) * EDIM + c0 + ac);
                const float4 v = *reinterpret_cast<const float4*>(emb + (size_t)(n0A + aj) * EDIM + c0 + ac + 4);
                a_lds[ac + 0][aj] = u.x; a_lds[ac + 1][aj] = u.y;
                a_lds[ac + 2][aj] = u.z; a_lds[ac + 3][aj] = u.w;
                a_lds[ac + 4][aj] = v.x; a_lds[ac + 5][aj] = v.y;
                a_lds[ac + 6][aj] = v.z; a_lds[ac + 7][aj] = v.w;
            }
            {   // B: b_lds[k][j] = emb[(m0+j)*256 + c0 + k]
                const float4 u = *reinterpret_cast<const float4*>(emb + (size_t)(m0 + aj) * EDIM + c0 + ac);
                const float4 v = *reinterpret_cast<const float4*>(emb + (size_t)(m0 + aj) * EDIM + c0 + ac + 4);
                b_lds[ac + 0][aj] = u.x; b_lds[ac + 1][aj] = u.y;
                b_lds[ac + 2][aj] = u.z; b_lds[ac + 3][aj] = u.w;
                b_lds[ac + 4][aj] = v.x; b_lds[ac + 5][aj] = v.y;
                b_lds[ac + 6][aj] = v.z; b_lds[ac + 7][aj] = v.w;
            }
            __syncthreads();
            #pragma unroll
            for (int k = 0; k < 16; ++k) {
                const float4 a0 = *reinterpret_cast<const float4*>(&a_lds[k][ty * 4]);
                const float4 a1 = *reinterpret_cast<const float4*>(&a_lds[k][64 + ty * 4]);
                const float4 b0 = *reinterpret_cast<const float4*>(&b_lds[k][tx * 4]);
                const float4 b1 = *reinterpret_cast<const float4*>(&b_lds[k][64 + tx * 4]);
                const float av[8] = {a0.x, a0.y, a0.z, a0.w, a1.x, a1.y, a1.z, a1.w};
                const float bv[8] = {b0.x, b0.y, b0.z, b0.w, b1.x, b1.y, b1.z, b1.w};
                #pragma unroll
                for (int r = 0; r < 8; ++r)
                    #pragma unroll
                    for (int c = 0; c < 8; ++c)
                        acc[r][c] = fmaf(av[r], bv[c], acc[r][c]);
            }
        }
        const float4 e0 = *reinterpret_cast<const float4*>(&e2[m0 + tx * 4]);
        const float4 e1 = *reinterpret_cast<const float4*>(&e2[m0 + 64 + tx * 4]);
        const float eb[8] = {e0.x, e0.y, e0.z, e0.w, e1.x, e1.y, e1.z, e1.w};
        #pragma unroll
        for (int r = 0; r < 8; ++r) {
            #pragma unroll
            for (int c = 0; c < 8; ++c) {
                const float d = (eb[c] + e2a[r]) - 2.0f * acc[r][c];
                if (d < v1[r]) { v2[r] = v1[r]; v1[r] = d; }
                else if (d < v2[r]) { v2[r] = d; }
            }
        }
    }
    // merge two-smallest across tx lanes
    #pragma unroll
    for (int r = 0; r < 8; ++r) {
        #pragma unroll
        for (int m = 1; m < 16; m <<= 1) {
            const float o1 = __shfl_xor(v1[r], m);
            const float o2 = __shfl_xor(v2[r], m);
            const float nv1 = fminf(v1[r], o1);
            const float nv2 = fminf(fmaxf(v1[r], o1), fminf(v2[r], o2));
            v1[r] = nv1; v2[r] = nv2;
        }
        if (tx == 0) {
            const int n = n0A + row8(ty, r);
            d1p[((size_t)blockIdx.y * N_E + n) * 2 + 0] = v1[r];
            d1p[((size_t)blockIdx.y * N_E + n) * 2 + 1] = v2[r];
        }
    }
}

// ---------------- unpack packed min -> idx / dmin / indices output ----------------
__global__ void k_unpack(const unsigned long long* __restrict__ pmin,
                         int* __restrict__ idxi, float* __restrict__ dmin,
                         float* __restrict__ out_idx) {
    int i = blockIdx.x * 256 + threadIdx.x;
    unsigned long long p = pmin[i];
    int idx  = (int)(p & 0xFFFFFFFFull);
    idxi[i]  = idx;
    dmin[i]  = __uint_as_float((unsigned)(p >> 32));
    out_idx[i] = (float)idx;
}

// ---------------- gather + straight-through + MSE accumulation ----------------
__global__ void k_epilogue(const float* __restrict__ z, const float* __restrict__ emb,
                           const int* __restrict__ idxi,
                           float* __restrict__ out_zq, float* __restrict__ out_zfl,
                           double* __restrict__ mse) {
    const int j4 = blockIdx.x * 256 + threadIdx.x;   // float4 index into bchw
    const int j  = j4 * 4;
    const int b  = j >> 18;
    const int c  = (j >> 10) & 255;
    const int hw = j & 1023;
    const int ib = (b << 10) + hw;
    const float4 zv = *reinterpret_cast<const float4*>(z + j);
    const float q0 = emb[(size_t)idxi[ib + 0] * EDIM + c];
    const float q1 = emb[(size_t)idxi[ib + 1] * EDIM + c];
    const float q2 = emb[(size_t)idxi[ib + 2] * EDIM + c];
    const float q3 = emb[(size_t)idxi[ib + 3] * EDIM + c];
    const float d0 = q0 - zv.x, d1 = q1 - zv.y, d2 = q2 - zv.z, d3 = q3 - zv.w;
    // straight-through: z + (q - z), fp32 rounding preserved (NOT just q)
    const float4 st = {zv.x + d0, zv.y + d1, zv.z + d2, zv.w + d3};
    *reinterpret_cast<float4*>(out_zq + j) = st;
    // out_zfl base has odd float offset -> scalar stores (alignment)
    out_zfl[j + 0] = st.x; out_zfl[j + 1] = st.y; out_zfl[j + 2] = st.z; out_zfl[j + 3] = st.w;

    double s = (double)(d0 * d0) + (double)(d1 * d1) + (double)(d2 * d2) + (double)(d3 * d3);
    #pragma unroll
    for (int m = 32; m; m >>= 1) s += __shfl_down(s, m);
    __shared__ double part[4];
    if ((threadIdx.x & 63) == 0) part[threadIdx.x >> 6] = s;
    __syncthreads();
    if (threadIdx.x == 0) atomicAdd(mse, part[0] + part[1] + part[2] + part[3]);
}

// ---------------- distances output [b,w] (underflows to 0, computed faithfully) ----
__global__ void k_distances(const float* __restrict__ dmin, float* __restrict__ out_d) {
    int t = threadIdx.x;            // 512 threads
    int b = t >> 5, w = t & 31;
    float s = 0.f;
    #pragma unroll
    for (int h = 0; h < HH; ++h) {
        float d = dmin[(b << 10) + (h << 5) + w];
        s += d * d;
    }
    float mean = s * (1.0f / 32.0f);
    out_d[t] = expf(-mean / 0.02f);
}

// ---------------- finalize: min_dist merge, tmd, cbvar, loss ----------------
__global__ void k_finalize(const float* __restrict__ d1p, const double* __restrict__ mse,
                           float* __restrict__ out) {
    const int t = threadIdx.x;      // 256 threads, 1 block
    double s = 0.0, ss = 0.0;
    for (int n = t; n < N_E; n += 256) {
        float v1 = 3.4e38f, v2 = 3.4e38f;
        #pragma unroll
        for (int sp = 0; sp < 8; ++sp) {
            const float a1 = d1p[((size_t)sp * N_E + n) * 2 + 0];
            const float a2 = d1p[((size_t)sp * N_E + n) * 2 + 1];
            const float n1 = fminf(v1, a1);
            const float n2 = fminf(fmaxf(v1, a1), fminf(v2, a2));
            v1 = n1; v2 = n2;
        }
        s  += (double)v2;
        ss += (double)v2 * (double)v2;
    }
    #pragma unroll
    for (int m = 32; m; m >>= 1) { s += __shfl_down(s, m); ss += __shfl_down(ss, m); }
    __shared__ double rs[4], rss[4];
    if ((t & 63) == 0) { rs[t >> 6] = s; rss[t >> 6] = ss; }
    __syncthreads();
    if (t == 0) {
        const double S  = rs[0] + rs[1] + rs[2] + rs[3];
        const double SS = rss[0] + rss[1] + rss[2] + rss[3];
        const float tmd = (float)S;
        double var = (SS - S * S / (double)N_E) / (double)(N_E - 1);
        if (var < 0.0) var = 0.0;
        const float cbv = (float)sqrt(var);
        const float m1  = (float)(*mse / (double)NELEM);
        const float lossf = m1 + 0.25f * m1 - tmd;
        out[O_LOSS] = lossf;
        out[O_CBV]  = cbv;
        out[O_TMD]  = tmd;
    }
}

extern "C" void kernel_launch(void* const* d_in, const int* in_sizes, int n_in,
                              void* d_out, int out_size, void* d_ws, size_t ws_size,
                              hipStream_t stream) {
    const float* z   = (const float*)d_in[0];
    const float* emb = (const float*)d_in[1];
    float* out = (float*)d_out;
    char*  ws  = (char*)d_ws;

    unsigned long long* pmin = (unsigned long long*)(ws + WS_PMIN);
    int*    idxi = (int*)   (ws + WS_IDX);
    float*  dmin = (float*) (ws + WS_DMIN);
    float*  e2   = (float*) (ws + WS_E2);
    float*  z2   = (float*) (ws + WS_Z2);
    double* mse  = (double*)(ws + WS_MSE);
    float*  d1p  = (float*) (ws + WS_D1P);

    k_init     <<<64,   256, 0, stream>>>(pmin, mse);
    k_e2       <<<2048, 256, 0, stream>>>(emb, e2);
    k_z2       <<<64,   256, 0, stream>>>(z, z2);
    k_gemm_z   <<<dim3(128, 8), 256, 0, stream>>>(z, emb, z2, e2, pmin);
    k_gemm_d1  <<<dim3(64, 8),  256, 0, stream>>>(emb, e2, d1p);
    k_unpack   <<<64,   256, 0, stream>>>(pmin, idxi, dmin, out + O_IDX);
    k_epilogue <<<4096, 256, 0, stream>>>(z, emb, idxi, out + O_ZQ, out + O_ZFL, mse);
    k_distances<<<1,    512, 0, stream>>>(dmin, out + O_DIST);
    k_finalize <<<1,    256, 0, stream>>>(d1p, mse, out);
}

// Round 3
// 1165.068 us; speedup vs baseline: 1.1875x; 1.1875x over previous
//
#include <hip/hip_runtime.h>
#include <stdint.h>

// ---------------- problem constants ----------------
#define N_E   8192
#define EDIM  256
#define NB    16
#define HH    32
#define WW    32
#define HW    1024            // H*W
#define NI    16384           // NB*HW (rows of zf)
#define NELEM 4194304         // NB*EDIM*HW

#define MARGIN    2.5e-4f     // z-path candidate margin vs bf16-mfma error (~40 sigma)
#define MARGIN_D1 2e-8f       // d1-path margin (~100 sigma of bf16 dot error)
#define ITEM_CAP  262144

// output flat offsets (reference return order)
#define O_ZQ   0
#define O_LOSS 4194304
#define O_DIST 4194305
#define O_IDX  4194817
#define O_ZFL  4211201
#define O_CBV  8405505
#define O_TMD  8405506

// workspace byte offsets (total ~31.4 MB, same footprint as R1)
#define WS_PMIN  0            // u64  * 16384
#define WS_IDX   131072       // i32  * 16384
#define WS_DMIN  196608       // f32  * 16384
#define WS_E2    262144       // f32  * 8192
#define WS_Z2    294912       // f32  * 16384
#define WS_MSE   360448       // double
#define WS_CNT   360456       // int
#define WS_MIND  360512       // f32  * 8192 (min_dist; reuses old d1p region)
#define WS_ZA    1048576      // bf16 * 16384*256 fragment-major (8 MB)
#define WS_EB    9437184      // bf16 * 8192*256 fragment-major (4 MB)
#define WS_M     13631488     // f32  * 16384*256 (16 MB); reused as md1[8192][256] later
#define WS_ITEMS 30408704     // u32  * ITEM_CAP (1 MB)

typedef __attribute__((ext_vector_type(8))) short bf16x8;
typedef __attribute__((ext_vector_type(4))) float f32x4;

__device__ __forceinline__ short f2bf(float f) {   // round-to-nearest-even
    unsigned u = __float_as_uint(f);
    u += 0x7fffu + ((u >> 16) & 1u);
    return (short)(u >> 16);
}

// ---------------- init (ws is poisoned 0xAA every launch) ----------------
__global__ void k_init(unsigned long long* __restrict__ pmin, double* __restrict__ mse,
                       int* __restrict__ cnt) {
    int t = blockIdx.x * 256 + threadIdx.x;
    if (t < NI) pmin[t] = 0xFFFFFFFFFFFFFFFFull;
    if (t == 0) { *mse = 0.0; *cnt = 0; }
}

// ---------------- e2[n] = sum_c emb[n,c]^2 ----------------
__global__ void k_e2(const float* __restrict__ emb, float* __restrict__ e2) {
    int row  = blockIdx.x * 4 + (threadIdx.x >> 6);
    int lane = threadIdx.x & 63;
    float4 v = *reinterpret_cast<const float4*>(emb + (size_t)row * EDIM + lane * 4);
    float s = v.x * v.x + v.y * v.y + v.z * v.z + v.w * v.w;
    #pragma unroll
    for (int m = 32; m; m >>= 1) s += __shfl_xor(s, m);
    if (lane == 0) e2[row] = s;
}

// ---------------- z2[i] = sum_c z[b,c,h,w]^2  (i = b*1024+hw) ----------------
__global__ void k_z2(const float* __restrict__ z, float* __restrict__ z2) {
    int i = blockIdx.x * 256 + threadIdx.x;
    int b = i >> 10, hw = i & 1023;
    const float* p = z + (size_t)b * EDIM * HW + hw;
    float s = 0.f;
    #pragma unroll 8
    for (int c = 0; c < EDIM; ++c) { float v = p[(size_t)c * HW]; s += v * v; }
    z2[i] = s;
}

// ---------------- z (b,c,hw) -> zA bf16 fragment-major ----------------
// zA[(ig*32 + kq)*16 + r] = bf16x8 of z row i=ig*16+r, c=kq*8..+7
// A-frag for 16x16x32: lane l holds row=l&15, k=(l>>4)*8+j
__global__ void k_convert_z(const float* __restrict__ z, bf16x8* __restrict__ zA) {
    __shared__ float lds[64][65];
    const int t   = threadIdx.x;
    const int hw0 = blockIdx.x * 64;
    const int c0  = blockIdx.y * 64;
    const int b   = blockIdx.z;
    #pragma unroll
    for (int cc = 0; cc < 4; ++cc) {
        const int cl = cc * 16 + (t >> 4);
        const float4 v = *reinterpret_cast<const float4*>(
            z + ((size_t)(b * 256 + c0 + cl) << 10) + hw0 + (t & 15) * 4);
        lds[cl][(t & 15) * 4 + 0] = v.x; lds[cl][(t & 15) * 4 + 1] = v.y;
        lds[cl][(t & 15) * 4 + 2] = v.z; lds[cl][(t & 15) * 4 + 3] = v.w;
    }
    __syncthreads();
    const int hl = t & 63;
    const int i  = b * 1024 + hw0 + hl;
    const int ig = i >> 4, r = i & 15;
    #pragma unroll
    for (int half = 0; half < 2; ++half) {
        const int kqi = (t >> 6) + half * 4;          // 0..7 local kq
        const int kq  = (c0 >> 3) + kqi;
        bf16x8 o;
        #pragma unroll
        for (int j = 0; j < 8; ++j) o[j] = f2bf(lds[kqi * 8 + j][hl]);
        zA[(ig * 32 + kq) * 16 + r] = o;
    }
}

// ---------------- emb (n,c) -> eB bf16 fragment-major ----------------
// eB[(g*32 + kq)*16 + c16] = bf16x8 of emb row n=g*16+c16, c=kq*8..+7
// (serves as BOTH A- and B-operand fragments: identical lane layout)
__global__ void k_convert_e(const float* __restrict__ emb, bf16x8* __restrict__ eB) {
    const int t  = threadIdx.x;
    const int kq = t & 31;
    const int n  = blockIdx.x * 8 + (t >> 5);
    const float4 u = *reinterpret_cast<const float4*>(emb + (size_t)n * EDIM + kq * 8);
    const float4 v = *reinterpret_cast<const float4*>(emb + (size_t)n * EDIM + kq * 8 + 4);
    bf16x8 o;
    o[0] = f2bf(u.x); o[1] = f2bf(u.y); o[2] = f2bf(u.z); o[3] = f2bf(u.w);
    o[4] = f2bf(v.x); o[5] = f2bf(v.y); o[6] = f2bf(v.z); o[7] = f2bf(v.w);
    eB[((n >> 4) * 32 + kq) * 16 + (n & 15)] = o;
}

// ---------------- MFMA candidate pass (z path) ----------------
// S[i,n] = dot(z_i, e_n) via bf16 MFMA; per-(row, 32-col group) min of
// (e2[n] - 2 S) -> m[row][256]. z2 is row-constant: drops out of argmin.
__launch_bounds__(256, 2)
__global__ void k_cand(const bf16x8* __restrict__ zA, const bf16x8* __restrict__ eB,
                       const float* __restrict__ e2, float* __restrict__ m) {
    const int t = threadIdx.x;
    const int w = t >> 6, l = t & 63;
    const int lo16 = l & 15, hi4 = l >> 4;
    const int iblk = blockIdx.x, chunk = blockIdx.y;
    const int ig0 = (iblk * 128 + w * 32) >> 4;

    bf16x8 a[2][8];
    #pragma unroll
    for (int ig = 0; ig < 2; ++ig)
        #pragma unroll
        for (int st = 0; st < 8; ++st)
            a[ig][st] = zA[((ig0 + ig) * 32 + st * 4 + hi4) * 16 + lo16];

    for (int ns = 0; ns < 8; ++ns) {
        const int n0 = chunk * 1024 + ns * 128;
        f32x4 acc[2][8];
        #pragma unroll
        for (int ig = 0; ig < 2; ++ig)
            #pragma unroll
            for (int cg = 0; cg < 8; ++cg) acc[ig][cg] = (f32x4){0.f, 0.f, 0.f, 0.f};
        float e2v[8];
        #pragma unroll
        for (int cg = 0; cg < 8; ++cg) e2v[cg] = e2[n0 + cg * 16 + lo16];

        #pragma unroll
        for (int st = 0; st < 8; ++st) {
            #pragma unroll
            for (int cg = 0; cg < 8; ++cg) {
                const bf16x8 b = eB[(((n0 >> 4) + cg) * 32 + st * 4 + hi4) * 16 + lo16];
                acc[0][cg] = __builtin_amdgcn_mfma_f32_16x16x32_bf16(a[0][st], b, acc[0][cg], 0, 0, 0);
                acc[1][cg] = __builtin_amdgcn_mfma_f32_16x16x32_bf16(a[1][st], b, acc[1][cg], 0, 0, 0);
            }
        }
        // C/D layout: col=lane&15, row=(lane>>4)*4+reg  [m89-verified]
        #pragma unroll
        for (int ig = 0; ig < 2; ++ig) {
            #pragma unroll
            for (int reg = 0; reg < 4; ++reg) {
                const int row = iblk * 128 + w * 32 + ig * 16 + hi4 * 4 + reg;
                #pragma unroll
                for (int gp = 0; gp < 4; ++gp) {
                    float v = fminf(fmaf(-2.f, acc[ig][2 * gp][reg],     e2v[2 * gp]),
                                    fmaf(-2.f, acc[ig][2 * gp + 1][reg], e2v[2 * gp + 1]));
                    v = fminf(v, __shfl_xor(v, 1));
                    v = fminf(v, __shfl_xor(v, 2));
                    v = fminf(v, __shfl_xor(v, 4));
                    v = fminf(v, __shfl_xor(v, 8));
                    if (lo16 == gp) m[row * 256 + chunk * 32 + ns * 4 + gp] = v;
                }
            }
        }
    }
}

// ---------------- MFMA candidate pass (d1 path): both operands = eB ----------
// approx(n, m-group) = min over group of (e2[m] - 2 dot(emb_n, emb_m))
__launch_bounds__(256, 2)
__global__ void k_cand_d1(const bf16x8* __restrict__ eB, const float* __restrict__ e2,
                          float* __restrict__ md1) {
    const int t = threadIdx.x;
    const int w = t >> 6, l = t & 63;
    const int lo16 = l & 15, hi4 = l >> 4;
    const int iblk = blockIdx.x, chunk = blockIdx.y;
    const int ig0 = (iblk * 128 + w * 32) >> 4;

    bf16x8 a[2][8];
    #pragma unroll
    for (int ig = 0; ig < 2; ++ig)
        #pragma unroll
        for (int st = 0; st < 8; ++st)
            a[ig][st] = eB[((ig0 + ig) * 32 + st * 4 + hi4) * 16 + lo16];

    for (int ns = 0; ns < 8; ++ns) {
        const int n0 = chunk * 1024 + ns * 128;   // m-range here
        f32x4 acc[2][8];
        #pragma unroll
        for (int ig = 0; ig < 2; ++ig)
            #pragma unroll
            for (int cg = 0; cg < 8; ++cg) acc[ig][cg] = (f32x4){0.f, 0.f, 0.f, 0.f};
        float e2v[8];
        #pragma unroll
        for (int cg = 0; cg < 8; ++cg) e2v[cg] = e2[n0 + cg * 16 + lo16];

        #pragma unroll
        for (int st = 0; st < 8; ++st) {
            #pragma unroll
            for (int cg = 0; cg < 8; ++cg) {
                const bf16x8 b = eB[(((n0 >> 4) + cg) * 32 + st * 4 + hi4) * 16 + lo16];
                acc[0][cg] = __builtin_amdgcn_mfma_f32_16x16x32_bf16(a[0][st], b, acc[0][cg], 0, 0, 0);
                acc[1][cg] = __builtin_amdgcn_mfma_f32_16x16x32_bf16(a[1][st], b, acc[1][cg], 0, 0, 0);
            }
        }
        #pragma unroll
        for (int ig = 0; ig < 2; ++ig) {
            #pragma unroll
            for (int reg = 0; reg < 4; ++reg) {
                const int row = iblk * 128 + w * 32 + ig * 16 + hi4 * 4 + reg;   // = n
                #pragma unroll
                for (int gp = 0; gp < 4; ++gp) {
                    float v = fminf(fmaf(-2.f, acc[ig][2 * gp][reg],     e2v[2 * gp]),
                                    fmaf(-2.f, acc[ig][2 * gp + 1][reg], e2v[2 * gp + 1]));
                    v = fminf(v, __shfl_xor(v, 1));
                    v = fminf(v, __shfl_xor(v, 2));
                    v = fminf(v, __shfl_xor(v, 4));
                    v = fminf(v, __shfl_xor(v, 8));
                    if (lo16 == gp) md1[row * 256 + chunk * 32 + ns * 4 + gp] = v;
                }
            }
        }
    }
}

// ---------------- z-path select: rowmin over 256 groups, emit within margin ----
__global__ void k_select(const float* __restrict__ m, int* __restrict__ cnt,
                         unsigned* __restrict__ items) {
    const int t = threadIdx.x;
    const int row = blockIdx.x * 4 + (t >> 6);
    const int l = t & 63;
    const float4 mv = reinterpret_cast<const float4*>(m + (size_t)row * 256)[l];
    float v = fminf(fminf(mv.x, mv.y), fminf(mv.z, mv.w));
    #pragma unroll
    for (int o = 32; o; o >>= 1) v = fminf(v, __shfl_xor(v, o));
    const float thr = v + MARGIN;
    if (mv.x <= thr) { int p = atomicAdd(cnt, 1); if (p < ITEM_CAP) items[p] = (row << 8) | (l * 4 + 0); }
    if (mv.y <= thr) { int p = atomicAdd(cnt, 1); if (p < ITEM_CAP) items[p] = (row << 8) | (l * 4 + 1); }
    if (mv.z <= thr) { int p = atomicAdd(cnt, 1); if (p < ITEM_CAP) items[p] = (row << 8) | (l * 4 + 2); }
    if (mv.w <= thr) { int p = atomicAdd(cnt, 1); if (p < ITEM_CAP) items[p] = (row << 8) | (l * 4 + 3); }
}

// ---------------- exact fp32 rescore of z-path candidates ----------------
__global__ void k_rescore(const float* __restrict__ z, const float* __restrict__ emb,
                          const float* __restrict__ z2, const float* __restrict__ e2,
                          const int* __restrict__ cnt, const unsigned* __restrict__ items,
                          unsigned long long* __restrict__ pmin) {
    const int t = threadIdx.x;
    const int l = t & 63;
    const int wid = blockIdx.x * 4 + (t >> 6);
    int n_items = *cnt; if (n_items > ITEM_CAP) n_items = ITEM_CAP;
    for (int it = wid; it < n_items; it += 16384) {
        const unsigned item = items[it];
        const int row = item >> 8, g = item & 255;
        const int n = g * 32 + (l & 31);
        const int half = l >> 5;
        const float* zp = z + ((size_t)(row >> 10) << 18) + (row & 1023) + (size_t)(half * 128) * HW;
        const float* ep = emb + (size_t)n * EDIM + half * 128;
        float acc = 0.f;
        #pragma unroll 8
        for (int c = 0; c < 128; ++c) acc = fmaf(zp[(size_t)c * HW], ep[c], acc);
        acc += __shfl_xor(acc, 32);                       // full 256-dot
        const float t0 = z2[row] + e2[n];
        const float d  = fmaf(-2.f, acc, t0);             // == t0 - 2*acc (2*acc exact)
        unsigned long long pk = ((unsigned long long)__float_as_uint(d) << 32) | (unsigned)n;
        #pragma unroll
        for (int o = 1; o < 64; o <<= 1) {
            const unsigned long long op = __shfl_xor(pk, o);
            if (op < pk) pk = op;
        }
        if (l == 0) atomicMin(&pmin[row], pk);
    }
}

// ---------------- d1 final: per column n, exact 2nd-smallest ----------------
// thr = 2nd-smallest group-min + margin (provably over-inclusive); rescore
// candidate groups with the SAME sequential-256 fmaf chain as the fp32 kernel.
__global__ void k_d1_final(const float* __restrict__ emb, const float* __restrict__ e2,
                           const float* __restrict__ md1, float* __restrict__ mind) {
    const int t = threadIdx.x, l = t & 63;
    const int n = blockIdx.x * 4 + (t >> 6);
    const float4 mv = reinterpret_cast<const float4*>(md1 + (size_t)n * 256)[l];
    // two smallest of the lane's 4 values
    const float lo1 = fminf(mv.x, mv.y), hi1 = fmaxf(mv.x, mv.y);
    const float lo2 = fminf(mv.z, mv.w), hi2 = fmaxf(mv.z, mv.w);
    float a1 = fminf(lo1, lo2);
    float a2 = fminf(fmaxf(lo1, lo2), fminf(hi1, hi2));
    #pragma unroll
    for (int o = 1; o < 64; o <<= 1) {
        const float o1 = __shfl_xor(a1, o), o2 = __shfl_xor(a2, o);
        const float n1 = fminf(a1, o1);
        const float n2 = fminf(fmaxf(a1, o1), fminf(a2, o2));
        a1 = n1; a2 = n2;
    }
    const float thr = a2 + MARGIN_D1;
    const float e2n = e2[n];
    const float* np = emb + (size_t)n * EDIM;
    float b1 = 3.4e38f, b2 = 3.4e38f;
    const float slot[4] = {mv.x, mv.y, mv.z, mv.w};
    #pragma unroll
    for (int s = 0; s < 4; ++s) {
        unsigned long long mask = __ballot(slot[s] <= thr);
        while (mask) {
            const int src = __builtin_ctzll(mask); mask &= mask - 1;
            const int g = src * 4 + s;
            const int mm = g * 32 + (l & 31);
            const float* ep = emb + (size_t)mm * EDIM;
            float acc = 0.f;
            #pragma unroll 8
            for (int c = 0; c < EDIM; ++c) acc = fmaf(ep[c], np[c], acc);
            float dv = (e2[mm] + e2n) - 2.0f * acc;
            if (l >= 32) dv = 3.4e38f;                 // dedupe the half-wave copy
            if (dv < b1) { b2 = b1; b1 = dv; }
            else if (dv < b2) { b2 = dv; }
        }
    }
    #pragma unroll
    for (int o = 1; o < 64; o <<= 1) {
        const float o1 = __shfl_xor(b1, o), o2 = __shfl_xor(b2, o);
        const float n1 = fminf(b1, o1);
        const float n2 = fminf(fmaxf(b1, o1), fminf(b2, o2));
        b1 = n1; b2 = n2;
    }
    if (l == 0) mind[n] = b2;
}

// ---------------- unpack packed min -> idx / dmin / indices output ----------------
__global__ void k_unpack(const unsigned long long* __restrict__ pmin,
                         int* __restrict__ idxi, float* __restrict__ dmin,
                         float* __restrict__ out_idx) {
    int i = blockIdx.x * 256 + threadIdx.x;
    unsigned long long p = pmin[i];
    int idx  = (int)(p & 0xFFFFFFFFull);
    idxi[i]  = idx;
    dmin[i]  = __uint_as_float((unsigned)(p >> 32));
    out_idx[i] = (float)idx;
}

// ---------------- gather + straight-through + MSE accumulation ----------------
__global__ void k_epilogue(const float* __restrict__ z, const float* __restrict__ emb,
                           const int* __restrict__ idxi,
                           float* __restrict__ out_zq, float* __restrict__ out_zfl,
                           double* __restrict__ mse) {
    const int j4 = blockIdx.x * 256 + threadIdx.x;   // float4 index into bchw
    const int j  = j4 * 4;
    const int b  = j >> 18;
    const int c  = (j >> 10) & 255;
    const int hw = j & 1023;
    const int ib = (b << 10) + hw;
    const float4 zv = *reinterpret_cast<const float4*>(z + j);
    const float q0 = emb[(size_t)idxi[ib + 0] * EDIM + c];
    const float q1 = emb[(size_t)idxi[ib + 1] * EDIM + c];
    const float q2 = emb[(size_t)idxi[ib + 2] * EDIM + c];
    const float q3 = emb[(size_t)idxi[ib + 3] * EDIM + c];
    const float d0 = q0 - zv.x, d1 = q1 - zv.y, d2 = q2 - zv.z, d3 = q3 - zv.w;
    const float4 st = {zv.x + d0, zv.y + d1, zv.z + d2, zv.w + d3};  // z + (q-z)
    *reinterpret_cast<float4*>(out_zq + j) = st;
    out_zfl[j + 0] = st.x; out_zfl[j + 1] = st.y; out_zfl[j + 2] = st.z; out_zfl[j + 3] = st.w;

    double s = (double)(d0 * d0) + (double)(d1 * d1) + (double)(d2 * d2) + (double)(d3 * d3);
    #pragma unroll
    for (int m = 32; m; m >>= 1) s += __shfl_down(s, m);
    __shared__ double part[4];
    if ((threadIdx.x & 63) == 0) part[threadIdx.x >> 6] = s;
    __syncthreads();
    if (threadIdx.x == 0) atomicAdd(mse, part[0] + part[1] + part[2] + part[3]);
}

// ---------------- distances output [b,w] ----------------
__global__ void k_distances(const float* __restrict__ dmin, float* __restrict__ out_d) {
    int t = threadIdx.x;            // 512 threads
    int b = t >> 5, w = t & 31;
    float s = 0.f;
    #pragma unroll
    for (int h = 0; h < HH; ++h) {
        float d = dmin[(b << 10) + (h << 5) + w];
        s += d * d;
    }
    float mean = s * (1.0f / 32.0f);
    out_d[t] = expf(-mean / 0.02f);
}

// ---------------- finalize: tmd, cbvar, loss ----------------
__global__ void k_finalize(const float* __restrict__ mind, const double* __restrict__ mse,
                           float* __restrict__ out) {
    const int t = threadIdx.x;      // 256 threads, 1 block
    double s = 0.0, ss = 0.0;
    for (int n = t; n < N_E; n += 256) {
        const double v = (double)mind[n];
        s += v; ss += v * v;
    }
    #pragma unroll
    for (int m = 32; m; m >>= 1) { s += __shfl_down(s, m); ss += __shfl_down(ss, m); }
    __shared__ double rs[4], rss[4];
    if ((t & 63) == 0) { rs[t >> 6] = s; rss[t >> 6] = ss; }
    __syncthreads();
    if (t == 0) {
        const double S  = rs[0] + rs[1] + rs[2] + rs[3];
        const double SS = rss[0] + rss[1] + rss[2] + rss[3];
        const float tmd = (float)S;
        double var = (SS - S * S / (double)N_E) / (double)(N_E - 1);
        if (var < 0.0) var = 0.0;
        const float cbv = (float)sqrt(var);
        const float m1  = (float)(*mse / (double)NELEM);
        const float lossf = m1 + 0.25f * m1 - tmd;
        out[O_LOSS] = lossf;
        out[O_CBV]  = cbv;
        out[O_TMD]  = tmd;
    }
}

extern "C" void kernel_launch(void* const* d_in, const int* in_sizes, int n_in,
                              void* d_out, int out_size, void* d_ws, size_t ws_size,
                              hipStream_t stream) {
    const float* z   = (const float*)d_in[0];
    const float* emb = (const float*)d_in[1];
    float* out = (float*)d_out;
    char*  ws  = (char*)d_ws;

    unsigned long long* pmin = (unsigned long long*)(ws + WS_PMIN);
    int*      idxi  = (int*)    (ws + WS_IDX);
    float*    dmin  = (float*)  (ws + WS_DMIN);
    float*    e2    = (float*)  (ws + WS_E2);
    float*    z2    = (float*)  (ws + WS_Z2);
    double*   mse   = (double*) (ws + WS_MSE);
    int*      cnt   = (int*)    (ws + WS_CNT);
    float*    mind  = (float*)  (ws + WS_MIND);
    bf16x8*   zA    = (bf16x8*) (ws + WS_ZA);
    bf16x8*   eB    = (bf16x8*) (ws + WS_EB);
    float*    marr  = (float*)  (ws + WS_M);     // z-path group-mins, then md1
    unsigned* items = (unsigned*)(ws + WS_ITEMS);

    k_init     <<<64,   256, 0, stream>>>(pmin, mse, cnt);
    k_e2       <<<2048, 256, 0, stream>>>(emb, e2);
    k_z2       <<<64,   256, 0, stream>>>(z, z2);
    k_convert_z<<<dim3(16, 4, 16), 256, 0, stream>>>(z, zA);
    k_convert_e<<<1024, 256, 0, stream>>>(emb, eB);
    k_cand     <<<dim3(128, 8), 256, 0, stream>>>(zA, eB, e2, marr);
    k_select   <<<4096, 256, 0, stream>>>(marr, cnt, items);
    k_rescore  <<<4096, 256, 0, stream>>>(z, emb, z2, e2, cnt, items, pmin);
    // marr region is now free: reuse for md1 (stream-ordered)
    k_cand_d1  <<<dim3(64, 8), 256, 0, stream>>>(eB, e2, marr);
    k_d1_final <<<2048, 256, 0, stream>>>(emb, e2, marr, mind);
    k_unpack   <<<64,   256, 0, stream>>>(pmin, idxi, dmin, out + O_IDX);
    k_epilogue <<<4096, 256, 0, stream>>>(z, emb, idxi, out + O_ZQ, out + O_ZFL, mse);
    k_distances<<<1,    512, 0, stream>>>(dmin, out + O_DIST);
    k_finalize <<<1,    256, 0, stream>>>(mind, mse, out);
}